// Round 12
// baseline (99.090 us; speedup 1.0000x reference)
//
#include <hip/hip_runtime.h>
#include <math.h>
#include <stdint.h>

#define IMGS 64
#define HWDIM 512
#define KLEN 31
#define RAD 15
#define EPSV 1e-3f
#define MM_STRIDE 32   // ints per image slot (one 128B cache line each)

// ws layout (floats):
//   [0..31)     : separable weights s[i]  (kernel[i][j] = s_i*s_j)
//   [32..2080)  : per-image min/max int bits, 32-int stride
// d_out carries the pre-norm conv result, normalized in place by final_k.

typedef __attribute__((address_space(3))) uint8_t  lds_u8;
typedef const __attribute__((address_space(1))) uint8_t g_u8;

__global__ __launch_bounds__(128) void init_k(const float* __restrict__ gk,
                                              float* __restrict__ w,
                                              int* __restrict__ mm) {
    int t = threadIdx.x;
    if (t < KLEN) w[t] = sqrtf(gk[t * KLEN + t]);   // diag of s_i*s_j = s_i^2
    if (t < IMGS) { mm[t * MM_STRIDE] = 0x7F800000; mm[t * MM_STRIDE + 1] = 0; }
}

// ---------------- column-strip rolling pipeline ----------------
// Block owns a 64-col x 512-row strip. 17 h-chunks of 32 rows stream
// through double-buffered DMA staging (raw: 32 rows x 25 slots of 16B,
// row stride 100 floats == 4 mod 32 -> conflict-minimal). hconv writes a
// 96-row ring (stride 68 floats == 4 mod 32). Every 2 chunks, vconv
// emits 64 output rows. Raw s_barrier + explicit waitcnt keep the next
// chunk's global_load_lds in flight across barriers.

template <bool EDGE>
__device__ __forceinline__ void stage_chunk(const float* __restrict__ src,
                                            int x0, int c,
                                            float* __restrict__ buf, int t) {
    const int yb = 32 * c - RAD;
#pragma unroll
    for (int it = 0; it < 4; ++it) {
        const int idx = t + (it << 8);           // 0..1023, valid < 800
        if (idx < 800) {
            const int r = idx / 25;
            const int s = idx - r * 25;          // logical 16B slot in row
            int y = yb + r;
            y = y < 0 ? 0 : (y > HWDIM - 1 ? HWDIM - 1 : y);
            int g4 = (x0 >> 2) - 4 + s;
            if (EDGE) g4 = g4 < 0 ? 0 : (g4 > 127 ? 127 : g4);
            const float* gp = src + ((size_t)y << 9) + (g4 << 2);
            __builtin_amdgcn_global_load_lds((g_u8*)gp, (lds_u8*)&buf[idx << 2],
                                             16, 0, 0);
        }
    }
}

// hconv: 256 threads = 32 rows x 8 col-groups, 8 outputs/thread.
template <bool EDGE>
__device__ __forceinline__ void hconv_chunk(int c, const float* __restrict__ buf,
                                            float* __restrict__ ring,
                                            const float* __restrict__ wg,
                                            int x0, int t) {
    const int r  = t >> 3;                       // 0..31
    const int g2 = t & 7;                        // 8-col output group
    const int Y  = 32 * c - RAD + r;             // image row
    const bool vy = (unsigned)Y < HWDIM;
    float vv[40];                                // floats 8g2 .. 8g2+39
#pragma unroll
    for (int m = 0; m < 10; ++m) {
        const float4 v = *(const float4*)&buf[(r * 25 + (g2 << 1) + m) << 2];
        vv[4 * m + 0] = v.x; vv[4 * m + 1] = v.y;
        vv[4 * m + 2] = v.z; vv[4 * m + 3] = v.w;
    }
    const int cb = x0 - 16 + (g2 << 3);          // abs col of vv[0]
#pragma unroll
    for (int q = 0; q < 40; ++q) {
        float cv = fminf(fmaxf(vv[q], 0.f), 1.f);        // v_med3
        if (EDGE) cv = ((unsigned)(cb + q) < HWDIM) ? cv : 0.f;
        vv[q] = cv;
    }
    float o[8];
#pragma unroll
    for (int j = 0; j < 8; ++j) {
        float a = 0.f;
#pragma unroll
        for (int k = 0; k < KLEN; ++k) a += vv[1 + j + k] * wg[k];
        o[j] = vy ? a : 0.f;                     // zero pad rows
    }
    int R = 32 * (c % 3) + (96 - RAD) + r;       // == Y mod 96
    if (R >= 96) R -= 96;
    float* dst = &ring[R * 68 + (g2 << 3)];
    *(float4*)dst       = make_float4(o[0], o[1], o[2], o[3]);
    *(float4*)(dst + 4) = make_float4(o[4], o[5], o[6], o[7]);
}

// vconv chunk v: 64 rows x 64 cols; thread = 4-col x 4-row patch.
__device__ __forceinline__ void vconv_chunk(int v, const float* __restrict__ ring,
                                            const float* __restrict__ wg,
                                            float* __restrict__ dst, int x0, int t,
                                            float& lmin, float& lmax) {
    const int tx = t & 15;
    const int ty = t >> 4;
    float4 acc[4];
#pragma unroll
    for (int i = 0; i < 4; ++i) acc[i] = make_float4(0.f, 0.f, 0.f, 0.f);
    int R = (v % 3) * 64 + (96 - RAD) + (ty << 2);   // == (64v-15+4ty) mod 96
    if (R >= 96) R -= 96;
    if (R >= 96) R -= 96;
#pragma unroll
    for (int k = 0; k < 34; ++k) {
        const float4 vec = *(const float4*)&ring[R * 68 + (tx << 2)];
        ++R; if (R >= 96) R -= 96;
#pragma unroll
        for (int i = 0; i < 4; ++i) {
            const int j = k - i;                 // weight index, compile-time
            if (j >= 0 && j < KLEN) {
                const float w = wg[j];
                acc[i].x += vec.x * w;
                acc[i].y += vec.y * w;
                acc[i].z += vec.z * w;
                acc[i].w += vec.w * w;
            }
        }
    }
    const int yb = (v << 6) + (ty << 2);
#pragma unroll
    for (int i = 0; i < 4; ++i) {
        *(float4*)&dst[(size_t)(yb + i) * HWDIM + x0 + (tx << 2)] = acc[i];
        lmin = fminf(lmin, fminf(fminf(acc[i].x, acc[i].y), fminf(acc[i].z, acc[i].w)));
        lmax = fmaxf(lmax, fmaxf(fmaxf(acc[i].x, acc[i].y), fmaxf(acc[i].z, acc[i].w)));
    }
}

#define WBAR() { asm volatile("s_waitcnt vmcnt(0)" ::: "memory"); \
                 __builtin_amdgcn_s_barrier(); }
#define LBAR() { asm volatile("s_waitcnt lgkmcnt(0)" ::: "memory"); \
                 __builtin_amdgcn_s_barrier(); }

template <bool EDGE>
__device__ __forceinline__ void conv_body(const float* __restrict__ src,
                                          float* __restrict__ dst,
                                          const float* __restrict__ wg,
                                          int* __restrict__ mm, int img, int x0,
                                          float* __restrict__ rawA,
                                          float* __restrict__ rawB,
                                          float* __restrict__ ring,
                                          float* __restrict__ sred, int t) {
    float lmin = INFINITY, lmax = -INFINITY;

    stage_chunk<EDGE>(src, x0, 0, rawA, t);
    WBAR();                                      // chunk0 landed
    stage_chunk<EDGE>(src, x0, 1, rawB, t);      // fly under hconv(0)
    hconv_chunk<EDGE>(0, rawA, ring, wg, x0, t);
    WBAR();                                      // chunk1 landed; rawA free
    stage_chunk<EDGE>(src, x0, 2, rawA, t);
    hconv_chunk<EDGE>(1, rawB, ring, wg, x0, t);
#pragma unroll 1
    for (int v = 0; v < 7; ++v) {
        WBAR();                                  // chunk 2v+2 landed; rawB free
        stage_chunk<EDGE>(src, x0, 2 * v + 3, rawB, t);
        hconv_chunk<EDGE>(2 * v + 2, rawA, ring, wg, x0, t);
        LBAR();                                  // ring rows visible
        vconv_chunk(v, ring, wg, dst, x0, t, lmin, lmax);
        WBAR();                                  // chunk 2v+3 landed; rawA free
        stage_chunk<EDGE>(src, x0, 2 * v + 4, rawA, t);
        hconv_chunk<EDGE>(2 * v + 3, rawB, ring, wg, x0, t);
    }
    WBAR();                                      // chunk16 landed
    hconv_chunk<EDGE>(16, rawA, ring, wg, x0, t);
    LBAR();
    vconv_chunk(7, ring, wg, dst, x0, t, lmin, lmax);

    // wave butterfly -> block LDS reduce -> one atomic pair per block
#pragma unroll
    for (int off = 1; off < 64; off <<= 1) {
        lmin = fminf(lmin, __shfl_xor(lmin, off, 64));
        lmax = fmaxf(lmax, __shfl_xor(lmax, off, 64));
    }
    const int lane = t & 63, wid = t >> 6;
    if (lane == 0) { sred[wid] = lmin; sred[4 + wid] = lmax; }
    __syncthreads();
    if (t == 0) {
        float bmin = fminf(fminf(sred[0], sred[1]), fminf(sred[2], sred[3]));
        float bmax = fmaxf(fmaxf(sred[4], sred[5]), fmaxf(sred[6], sred[7]));
        // all values >= 0 -> float ordering == int-bits ordering
        atomicMin(&mm[img * MM_STRIDE], __float_as_int(bmin));
        atomicMax(&mm[img * MM_STRIDE + 1], __float_as_int(bmax));
    }
}

__global__ __launch_bounds__(256) void conv_k(const float* __restrict__ attn,
                                              float* __restrict__ out,
                                              const float* __restrict__ wg,
                                              int* __restrict__ mm) {
    __shared__ float rawA[800 * 4];              // 12.8 KB
    __shared__ float rawB[800 * 4];              // 12.8 KB
    __shared__ float ring[96 * 68];              // 26.1 KB
    __shared__ float sred[8];
    const int t = threadIdx.x;
    // XCD swizzle: XCD k (bid&7) owns 8 whole images.
    const int sw  = ((blockIdx.x & 7) << 6) | (blockIdx.x >> 3);
    const int img = sw >> 3;
    const int bx  = sw & 7;
    const int x0  = bx << 6;
    const float* src = attn + ((size_t)img << 18);
    float* dst = out + ((size_t)img << 18);
    if (bx == 0 || bx == 7)
        conv_body<true>(src, dst, wg, mm, img, x0, rawA, rawB, ring, sred, t);
    else
        conv_body<false>(src, dst, wg, mm, img, x0, rawA, rawB, ring, sred, t);
}

// out = max((out - mn) / max(mx - mn, eps), clip(attn,0,1)), in place.
__global__ __launch_bounds__(256) void final_k(const float* __restrict__ attn,
                                               float* __restrict__ out,
                                               const int* __restrict__ mm) {
    const int img = blockIdx.x >> 6;             // 64 blocks of 4096 elems/image
    const float mn = __int_as_float(mm[img * MM_STRIDE]);
    const float mx = __int_as_float(mm[img * MM_STRIDE + 1]);
    const float inv = 1.0f / fmaxf(mx - mn, EPSV);
    const size_t base0 = ((size_t)blockIdx.x << 12) + ((size_t)threadIdx.x << 2);
#pragma unroll
    for (int h = 0; h < 4; ++h) {
        const size_t base = base0 + (size_t)h * 1024;
        float4 s = *(const float4*)(out + base);
        float4 a = *(const float4*)(attn + base);
        float4 o;
        o.x = fmaxf((s.x - mn) * inv, fminf(fmaxf(a.x, 0.f), 1.f));
        o.y = fmaxf((s.y - mn) * inv, fminf(fmaxf(a.y, 0.f), 1.f));
        o.z = fmaxf((s.z - mn) * inv, fminf(fmaxf(a.z, 0.f), 1.f));
        o.w = fmaxf((s.w - mn) * inv, fminf(fmaxf(a.w, 0.f), 1.f));
        *(float4*)(out + base) = o;
    }
}

extern "C" void kernel_launch(void* const* d_in, const int* in_sizes, int n_in,
                              void* d_out, int out_size, void* d_ws, size_t ws_size,
                              hipStream_t stream) {
    const float* attn = (const float*)d_in[0];
    const float* gk   = (const float*)d_in[1];
    float* out  = (float*)d_out;
    float* wsf  = (float*)d_ws;
    float* w1d  = wsf;
    int*   mm   = (int*)(wsf + 32);

    init_k<<<1, 128, 0, stream>>>(gk, w1d, mm);
    conv_k<<<512, 256, 0, stream>>>(attn, out, w1d, mm);
    final_k<<<IMGS * HWDIM * HWDIM / 4096, 256, 0, stream>>>(attn, out, mm);
}

// Round 13
// 78.760 us; speedup vs baseline: 1.2581x; 1.2581x over previous
//
#include <hip/hip_runtime.h>
#include <math.h>

#define IMGS 64
#define HWDIM 512
#define KLEN 31
#define RAD 15
#define EPSV 1e-3f
#define MM_STRIDE 32   // ints per image slot (one 128B cache line each)
#define ISTR 68        // inter row stride (floats): 68 == 4 (mod 32) -> <=2-way

// ws layout (floats):
//   [0..31)     : separable weights s[i]  (kernel[i][j] = s_i*s_j)
//   [32..2080)  : per-image min/max int bits, 32-int stride
// d_out carries the pre-norm conv result, normalized in place by final_k.

__global__ __launch_bounds__(128) void init_k(const float* __restrict__ gk,
                                              float* __restrict__ w,
                                              int* __restrict__ mm) {
    int t = threadIdx.x;
    if (t < KLEN) w[t] = sqrtf(gk[t * KLEN + t]);   // diag of s_i*s_j = s_i^2
    if (t < IMGS) { mm[t * MM_STRIDE] = 0x7F800000; mm[t * MM_STRIDE + 1] = 0; }
}

// ---- phase A helpers: item = (row r 0..93, quarter q 0..3) -> 16 h-outputs ----
template <bool EDGE>
__device__ __forceinline__ void loadA(int i, const float* __restrict__ src,
                                      int x0, int y0, float4* __restrict__ b) {
    const int r = i >> 2, q = i & 3;
    int y = y0 - RAD + r;
    if (EDGE) y = y < 0 ? 0 : (y > HWDIM - 1 ? HWDIM - 1 : y);
    const float4* row = (const float4*)(src + ((size_t)y << 9));
    const int gb = (x0 >> 2) + (q << 2) - 4;
#pragma unroll
    for (int m = 0; m < 12; ++m) {
        int g = gb + m;
        if (EDGE) g = g < 0 ? 0 : (g > 127 ? 127 : g);
        b[m] = row[g];
    }
}

template <bool EDGE>
__device__ __forceinline__ void compA(int i, int x0, int y0,
                                      const float* __restrict__ wg,
                                      float* __restrict__ inter,
                                      const float4* __restrict__ b) {
    const int r = i >> 2, q = i & 3;
    const int y = y0 - RAD + r;
    const int gb = (x0 >> 2) + (q << 2) - 4;
    const bool vy = !EDGE || ((unsigned)y < HWDIM);
    float vv[48];
#pragma unroll
    for (int m = 0; m < 12; ++m) {
        const bool vx = !EDGE || (vy && ((unsigned)(gb + m) < 128u));
        vv[4 * m + 0] = vx ? fminf(fmaxf(b[m].x, 0.f), 1.f) : 0.f;  // v_med3
        vv[4 * m + 1] = vx ? fminf(fmaxf(b[m].y, 0.f), 1.f) : 0.f;
        vv[4 * m + 2] = vx ? fminf(fmaxf(b[m].z, 0.f), 1.f) : 0.f;
        vv[4 * m + 3] = vx ? fminf(fmaxf(b[m].w, 0.f), 1.f) : 0.f;
    }
    float* dst = &inter[r * ISTR + (q << 4)];
#pragma unroll
    for (int d = 0; d < 4; ++d) {
        float4 o;
        float* op = &o.x;
#pragma unroll
        for (int s = 0; s < 4; ++s) {
            const int oc = (d << 2) + s;
            float a = 0.f;
#pragma unroll
            for (int k = 0; k < KLEN; ++k) a += vv[oc + 1 + k] * wg[k];
            op[s] = a;
        }
        *(float4*)(dst + (d << 2)) = o;
    }
}

// Fused separable 31x31 conv per 64x64 output tile.
// Phase A: hconv, 16 outputs/thread-item, both items' loads issued up front.
// Phase B: vconv from LDS -> pre-norm out + per-image min/max atomics.
template <bool EDGE>
__device__ __forceinline__ void conv_body(const float* __restrict__ attn,
                                          float* __restrict__ out,
                                          const float* __restrict__ wg,
                                          int* __restrict__ mm,
                                          int img, int x0, int y0,
                                          float* __restrict__ inter,
                                          float* __restrict__ sred) {
    const int t = threadIdx.x;
    const float* src = attn + ((size_t)img << 18);

    {   // ---- phase A: 376 items; thread t owns item t and (t<120) 256+t ----
        float4 bA[12], bB[12];
        const bool hasB = t < 120;
        loadA<EDGE>(t, src, x0, y0, bA);
        if (hasB) loadA<EDGE>(256 + t, src, x0, y0, bB);
        compA<EDGE>(t, x0, y0, wg, inter, bA);
        if (hasB) compA<EDGE>(256 + t, x0, y0, wg, inter, bB);
    }
    __syncthreads();

    // ---- phase B: vconv, each thread owns a 4-col x 4-row patch ----
    const int tx = t & 15;
    const int ty = t >> 4;
    float4 acc[4];
#pragma unroll
    for (int i = 0; i < 4; ++i) acc[i] = make_float4(0.f, 0.f, 0.f, 0.f);
#pragma unroll
    for (int k = 0; k < 34; ++k) {
        const float4 v = *(const float4*)&inter[((ty << 2) + k) * ISTR + (tx << 2)];
#pragma unroll
        for (int i = 0; i < 4; ++i) {
            const int j = k - i;                 // weight index, compile-time
            if (j >= 0 && j < KLEN) {
                const float w = wg[j];
                acc[i].x += v.x * w;
                acc[i].y += v.y * w;
                acc[i].z += v.z * w;
                acc[i].w += v.w * w;
            }
        }
    }
    float* dst = out + ((size_t)img << 18);
    float lmin = INFINITY, lmax = -INFINITY;
#pragma unroll
    for (int i = 0; i < 4; ++i) {
        *(float4*)&dst[(size_t)(y0 + (ty << 2) + i) * HWDIM + x0 + (tx << 2)] = acc[i];
        lmin = fminf(lmin, fminf(fminf(acc[i].x, acc[i].y), fminf(acc[i].z, acc[i].w)));
        lmax = fmaxf(lmax, fmaxf(fmaxf(acc[i].x, acc[i].y), fmaxf(acc[i].z, acc[i].w)));
    }
    // wave butterfly -> block LDS reduce -> one atomic pair per block
#pragma unroll
    for (int off = 1; off < 64; off <<= 1) {
        lmin = fminf(lmin, __shfl_xor(lmin, off, 64));
        lmax = fmaxf(lmax, __shfl_xor(lmax, off, 64));
    }
    const int lane = t & 63, wid = t >> 6;
    if (lane == 0) { sred[wid] = lmin; sred[4 + wid] = lmax; }
    __syncthreads();
    if (t == 0) {
        float bmin = fminf(fminf(sred[0], sred[1]), fminf(sred[2], sred[3]));
        float bmax = fmaxf(fmaxf(sred[4], sred[5]), fmaxf(sred[6], sred[7]));
        // all values >= 0 -> float ordering == int-bits ordering
        atomicMin(&mm[img * MM_STRIDE], __float_as_int(bmin));
        atomicMax(&mm[img * MM_STRIDE + 1], __float_as_int(bmax));
    }
}

__global__ __launch_bounds__(256, 2) void conv_k(const float* __restrict__ attn,
                                                 float* __restrict__ out,
                                                 const float* __restrict__ wg,
                                                 int* __restrict__ mm) {
    __shared__ float inter[94 * ISTR];           // 25.0 KB
    __shared__ float sred[8];
    // XCD swizzle: XCD k (bid&7) gets 512 contiguous work items = 8 whole
    // images -> halo re-reads stay in that XCD's L2.
    const int sw  = ((blockIdx.x & 7) << 9) + (blockIdx.x >> 3);
    const int img = sw >> 6;
    const int by  = (sw >> 3) & 7;
    const int bx  = sw & 7;
    const int x0 = bx << 6;
    const int y0 = by << 6;
    if (bx == 0 || bx == 7 || by == 0 || by == 7)
        conv_body<true>(attn, out, wg, mm, img, x0, y0, inter, sred);
    else
        conv_body<false>(attn, out, wg, mm, img, x0, y0, inter, sred);
}

// out = max((out - mn) / max(mx - mn, eps), clip(attn,0,1)), in place.
__global__ __launch_bounds__(256) void final_k(const float* __restrict__ attn,
                                               float* __restrict__ out,
                                               const int* __restrict__ mm) {
    const int img = blockIdx.x >> 6;             // 64 blocks of 4096 elems/image
    const float mn = __int_as_float(mm[img * MM_STRIDE]);
    const float mx = __int_as_float(mm[img * MM_STRIDE + 1]);
    const float inv = 1.0f / fmaxf(mx - mn, EPSV);
    const size_t base0 = ((size_t)blockIdx.x << 12) + ((size_t)threadIdx.x << 2);
#pragma unroll
    for (int h = 0; h < 4; ++h) {
        const size_t base = base0 + (size_t)h * 1024;
        float4 s = *(const float4*)(out + base);
        float4 a = *(const float4*)(attn + base);
        float4 o;
        o.x = fmaxf((s.x - mn) * inv, fminf(fmaxf(a.x, 0.f), 1.f));
        o.y = fmaxf((s.y - mn) * inv, fminf(fmaxf(a.y, 0.f), 1.f));
        o.z = fmaxf((s.z - mn) * inv, fminf(fmaxf(a.z, 0.f), 1.f));
        o.w = fmaxf((s.w - mn) * inv, fminf(fmaxf(a.w, 0.f), 1.f));
        *(float4*)(out + base) = o;
    }
}

extern "C" void kernel_launch(void* const* d_in, const int* in_sizes, int n_in,
                              void* d_out, int out_size, void* d_ws, size_t ws_size,
                              hipStream_t stream) {
    const float* attn = (const float*)d_in[0];
    const float* gk   = (const float*)d_in[1];
    float* out  = (float*)d_out;
    float* wsf  = (float*)d_ws;
    float* w1d  = wsf;
    int*   mm   = (int*)(wsf + 32);

    init_k<<<1, 128, 0, stream>>>(gk, w1d, mm);
    conv_k<<<4096, 256, 0, stream>>>(attn, out, w1d, mm);
    final_k<<<IMGS * HWDIM * HWDIM / 4096, 256, 0, stream>>>(attn, out, mm);
}